// Round 16
// baseline (65.879 us; speedup 1.0000x reference)
//
#include <hip/hip_runtime.h>
#include <hip/hip_bf16.h>
#include <hip/hip_fp16.h>
#include <stdint.h>

typedef __attribute__((ext_vector_type(8))) _Float16 f16x8;
typedef __attribute__((ext_vector_type(4))) float f32x4;
typedef __attribute__((ext_vector_type(4))) int i32x4;

#define GLD_LDS16(g, l) __builtin_amdgcn_global_load_lds( \
    (const __attribute__((address_space(1))) uint32_t*)(g), \
    (__attribute__((address_space(3))) uint32_t*)(l), 16, 0, 0)

// ---------------- W fp32 -> fp16 (into workspace), 512x2048 -------------
__global__ __launch_bounds__(256) void k_cvt_w(const float* __restrict__ W,
                                               _Float16* __restrict__ Wh) {
  int i = (blockIdx.x * 256 + threadIdx.x) * 8;  // 1048576 elems total
  float4 a = *(const float4*)(W + i);
  float4 b = *(const float4*)(W + i + 4);
  union { _Float16 h[8]; i32x4 v; } u;
  u.h[0] = (_Float16)a.x; u.h[1] = (_Float16)a.y;
  u.h[2] = (_Float16)a.z; u.h[3] = (_Float16)a.w;
  u.h[4] = (_Float16)b.x; u.h[5] = (_Float16)b.y;
  u.h[6] = (_Float16)b.z; u.h[7] = (_Float16)b.w;
  *(i32x4*)(Wh + i) = u.v;
}

__device__ inline float softplus_f(float x) {
  float e = __expf(-fabsf(x));
  return fmaxf(x, 0.f) + __logf(1.f + e);
}

// ---- fused GEMM(fp16 MFMA) + softplus-diff: IN-WAVE FRAG PIPELINE ----
// Geometry = R13/R15 (proven): block 128x256 (N-split 2), BK=64, 32 steps,
// 8 waves 2Mx4N, wave 64x64, XCD pairing, zero-conflict swizzles.
// R16 delta: every frag ds_read is issued one MFMA-cluster EARLY, so LDS
// read latency hides under MFMA in-wave (what barriers structurally
// prevented in R15). Rings: As x3, Bs x3 (both dist-2), araw x2, frag
// regs x2 sets. ONE barrier + ONE counted vmcnt(8) per step; compiler
// emits counted lgkmcnt for the IR ds_reads itself (m97 behavior).
__global__ __launch_bounds__(512, 2) void k_main(
    const float* __restrict__ X,      // [16384][2048]
    const _Float16* __restrict__ Wh,  // [512][2048]
    const float* __restrict__ U,      // [512][2]
    const float* __restrict__ hb,     // [512]
    float* __restrict__ Dp) {         // [2][16384] partial logit-diffs
  __shared__ __align__(16) _Float16 As[3][128 * 64];  // 3 x 16 KB
  __shared__ __align__(16) _Float16 Bs[3][256 * 64];  // 3 x 32 KB
  __shared__ float sD[128];

  const int t = threadIdx.x;
  const int lane = t & 63;
  const int wid = t >> 6;   // 0..7
  const int wm = wid >> 2;  // 0..1 (M half)
  const int wn = wid & 3;   // 0..3 (N quarter)
  const int bx = blockIdx.x;
  const int rt = (bx >> 4) * 8 + (bx & 7);  // row-tile 0..127
  const int nhalf = (bx >> 3) & 1;          // pair partner bx^8: same XCD
  const int bm0 = rt * 128;
  const int bn0 = nhalf * 256;
  const int lrow = lane & 15, lq = lane >> 4;

  if (t < 128) sD[t] = 0.f;

  f32x4 acc[4][4];
#pragma unroll
  for (int m = 0; m < 4; ++m)
#pragma unroll
    for (int n = 0; n < 4; ++n) acc[m][n] = (f32x4){0.f, 0.f, 0.f, 0.f};

  // A staging: thread -> row t>>2 (0..127), k-chunk16 t&3 (proven swizzle).
  const int arow = t >> 2, ach = t & 3;
  const float* xsrc = X + (size_t)(bm0 + arow) * 2048 + ach * 16;
  const int c0 = ach * 2;
  const int aw0 = arow * 128 + (((c0) ^ (arow & 7)) << 4);
  const int aw1 = arow * 128 + (((c0 + 1) ^ (arow & 7)) << 4);

  // B staging: wave wid rows [wid*32,+32), 4 gld_lds of 1KB, pre-swizzled
  // source (m173): phys slot s8 of row l8 holds chunk s8^l8.
  const int l8 = lane >> 3, s8 = lane & 7;
  const _Float16* bsrc =
      Wh + (size_t)(bn0 + wid * 32 + l8) * 2048 + (s8 ^ l8) * 8;
  char* const bd0 = (char*)&Bs[0][0] + wid * 4096;
  char* const bd1 = (char*)&Bs[1][0] + wid * 4096;
  char* const bd2 = (char*)&Bs[2][0] + wid * 4096;

  f32x4 arA[4], arB[4];              // A raw fp32, two named sets
  f16x8 fa0[4], fb0[4], fa1[4], fb1[4];  // frag pipeline, two sets

#define CVT_WRITE_A(ARC, Q) do {                                           \
    f16x8 hv0, hv1;                                                        \
    _Pragma("unroll") for (int j = 0; j < 4; ++j) {                        \
      hv0[j] = (_Float16)ARC[0][j]; hv0[j + 4] = (_Float16)ARC[1][j];      \
      hv1[j] = (_Float16)ARC[2][j]; hv1[j + 4] = (_Float16)ARC[3][j];      \
    }                                                                      \
    *(f16x8*)((char*)&As[Q][0] + aw0) = hv0;                               \
    *(f16x8*)((char*)&As[Q][0] + aw1) = hv1;                               \
  } while (0)

#define FRAGS_A(P, KS, FA) do {                                            \
    _Pragma("unroll") for (int mf = 0; mf < 4; ++mf) {                     \
      int row = wm * 64 + mf * 16 + lrow;                                  \
      int off = row * 128 + ((((KS)*4 + lq) ^ (row & 7)) << 4);            \
      FA[mf] = *(const f16x8*)((const char*)&As[P][0] + off);              \
    }                                                                      \
  } while (0)

#define FRAGS_B(P, KS, FB) do {                                            \
    _Pragma("unroll") for (int nf = 0; nf < 4; ++nf) {                     \
      int row = wn * 64 + nf * 16 + lrow;                                  \
      int off = row * 128 + ((((KS)*4 + lq) ^ (row & 7)) << 4);            \
      FB[nf] = *(const f16x8*)((const char*)&Bs[P][0] + off);              \
    }                                                                      \
  } while (0)

#define MFMA16(FA, FB) do {                                                \
    __builtin_amdgcn_s_setprio(1);                                         \
    _Pragma("unroll") for (int mf = 0; mf < 4; ++mf)                       \
      _Pragma("unroll") for (int nf = 0; nf < 4; ++nf)                     \
        acc[mf][nf] = __builtin_amdgcn_mfma_f32_16x16x32_f16(              \
            FA[mf], FB[nf], acc[mf][nf], 0, 0, 0);                         \
    __builtin_amdgcn_s_setprio(0);                                         \
  } while (0)

  // One K-step. Entry invariant: fa0/fb0 hold frags(KT,ks0); As[KT%3],
  // Bs[KT%3] valid+published; ARC holds A(KT+2); outstanding VMEM =
  // {B(KT+1)x4} older + nothing newer.
#define STEP(KT, ARL, ARC, P, Pn, Pw, BDW) do {                            \
    const int kb_ = ((KT) + 2 > 31) ? 31 : (KT) + 2;                       \
    const int ka_ = ((KT) + 3 > 31) ? 31 : (KT) + 3;                       \
    _Pragma("unroll") for (int i = 0; i < 4; ++i)   /* B(KT+2) DMA */      \
      GLD_LDS16(bsrc + (size_t)i * 16384 + (size_t)kb_ * 64,               \
                (BDW) + i * 1024);                                         \
    _Pragma("unroll") for (int c = 0; c < 4; ++c)   /* A(KT+3) -> regs */  \
      ARL[c] = *(const f32x4*)(xsrc + (size_t)ka_ * 64 + c * 4);           \
    FRAGS_A(P, 1, fa1);                             /* ks1 reads ... */    \
    FRAGS_B(P, 1, fb1);                                                    \
    MFMA16(fa0, fb0);                               /* ... hide under */   \
    CVT_WRITE_A(ARC, Pw);                           /* A(KT+2) -> LDS */   \
    FRAGS_A(Pn, 0, fa0);                            /* t+1 A prefetch */   \
    MFMA16(fa1, fb1);                                                      \
    asm volatile("s_waitcnt vmcnt(8)" ::: "memory"); /* drain B(KT+1) */   \
    __builtin_amdgcn_s_barrier();                                          \
    FRAGS_B(Pn, 0, fb0);                            /* t+1 B prefetch */   \
  } while (0)

  // ---- prologue ----
#pragma unroll
  for (int i = 0; i < 4; ++i)
    GLD_LDS16(bsrc + (size_t)i * 16384, bd0 + i * 1024);        // B(0)
#pragma unroll
  for (int i = 0; i < 4; ++i)
    GLD_LDS16(bsrc + (size_t)i * 16384 + 64, bd1 + i * 1024);   // B(1)
#pragma unroll
  for (int c = 0; c < 4; ++c) arA[c] = *(const f32x4*)(xsrc + c * 4);
  CVT_WRITE_A(arA, 0);                                          // A(0)
#pragma unroll
  for (int c = 0; c < 4; ++c) arA[c] = *(const f32x4*)(xsrc + 64 + c * 4);
  CVT_WRITE_A(arA, 1);                                          // A(1)
#pragma unroll
  for (int c = 0; c < 4; ++c) arA[c] = *(const f32x4*)(xsrc + 128 + c * 4);
  asm volatile("s_waitcnt vmcnt(0) lgkmcnt(0)" ::: "memory");   // prologue-only
  __builtin_amdgcn_s_barrier();
  FRAGS_A(0, 0, fa0);
  FRAGS_B(0, 0, fb0);
  // entry: arA=A(2); outstanding VMEM = 0 (B(1) already drained).

  // period-6 (araw parity x ring mod-3): 30 steps + 2 peeled
  for (int kt = 0; kt < 30; kt += 6) {
    STEP(kt + 0, arB, arA, 0, 1, 2, bd2);
    STEP(kt + 1, arA, arB, 1, 2, 0, bd0);
    STEP(kt + 2, arB, arA, 2, 0, 1, bd1);
    STEP(kt + 3, arA, arB, 0, 1, 2, bd2);
    STEP(kt + 4, arB, arA, 1, 2, 0, bd0);
    STEP(kt + 5, arA, arB, 2, 0, 1, bd1);
  }
  STEP(30, arB, arA, 0, 1, 2, bd2);  // dup prefetches land in dead slots
  STEP(31, arA, arB, 1, 2, 0, bd0);
#undef STEP
#undef MFMA16
#undef FRAGS_A
#undef FRAGS_B
#undef CVT_WRITE_A

  // ---- epilogue: softplus-difference partial for this N-half ----
  // acc[mf][nf][r]: row = bm0 + wm*64 + mf*16 + lq*4 + r
  //                 col = bn0 + wn*64 + nf*16 + lrow
  float dpart[16];
#pragma unroll
  for (int i = 0; i < 16; ++i) dpart[i] = 0.f;
#pragma unroll
  for (int nf = 0; nf < 4; ++nf) {
    int h = bn0 + wn * 64 + nf * 16 + lrow;
    float hbv = hb[h];
    float u0 = U[2 * h], u1 = U[2 * h + 1];
#pragma unroll
    for (int mf = 0; mf < 4; ++mf)
#pragma unroll
      for (int r = 0; r < 4; ++r) {
        float pf = acc[mf][nf][r] + hbv;
        dpart[mf * 4 + r] += softplus_f(pf + u0) - softplus_f(pf + u1);
      }
  }
#pragma unroll
  for (int i = 0; i < 16; ++i) {
    float v = dpart[i];
    v += __shfl_xor(v, 1);
    v += __shfl_xor(v, 2);
    v += __shfl_xor(v, 4);
    v += __shfl_xor(v, 8);
    dpart[i] = v;
  }
  if (lrow == 0) {
#pragma unroll
    for (int mf = 0; mf < 4; ++mf)
#pragma unroll
      for (int r = 0; r < 4; ++r)
        atomicAdd(&sD[wm * 64 + mf * 16 + lq * 4 + r], dpart[mf * 4 + r]);
  }
  __syncthreads();
  if (t < 128) Dp[nhalf * 16384 + bm0 + t] = sD[t];
}

// ---- combine the two N-half partials + sigmoid ----
__global__ __launch_bounds__(256) void k_final(const float* __restrict__ Dp,
                                               const float* __restrict__ yb,
                                               float* __restrict__ out) {
  int i = blockIdx.x * 256 + threadIdx.x;  // 0..16383
  float D = Dp[i] + Dp[16384 + i] + yb[0] - yb[1];  // logit0 - logit1
  float e = __expf(-D);
  float o0 = 1.f / (1.f + e);
  float o1 = e * o0;
  *(float2*)(out + (size_t)i * 2) = make_float2(o0, o1);
}

extern "C" void kernel_launch(void* const* d_in, const int* in_sizes, int n_in,
                              void* d_out, int out_size, void* d_ws,
                              size_t ws_size, hipStream_t stream) {
  const float* X = (const float*)d_in[0];
  const float* W = (const float*)d_in[1];
  const float* U = (const float*)d_in[2];
  const float* hb = (const float*)d_in[3];
  const float* yb = (const float*)d_in[4];
  float* out = (float*)d_out;
  _Float16* Wh = (_Float16*)d_ws;                       // 2 MB
  float* Dp = (float*)((char*)d_ws + 2 * 1024 * 1024);  // 128 KB partials

  hipLaunchKernelGGL(k_cvt_w, dim3(512), dim3(256), 0, stream, W, Wh);
  hipLaunchKernelGGL(k_main, dim3(256), dim3(512), 0, stream, X, Wh, U, hb, Dp);
  hipLaunchKernelGGL(k_final, dim3(64), dim3(256), 0, stream, Dp, yb, out);
}